// Round 2
// baseline (156.818 us; speedup 1.0000x reference)
//
#include <hip/hip_runtime.h>
#include <hip/hip_bf16.h>

// OctreeConv: out[N,64] = sum_k gather_k(input)[N,32] @ W[k][32,64]
// N=262144, C_IN=32, C_OUT=64, K3=27. bf16 MFMA (16x16x32), fp32 accumulate.
// Round 2: 64 octants/wave (4 A-tiles reuse each B-fragment), bf16 input
// pre-pass in d_ws to halve gather traffic and kill in-loop cvt.

typedef float  f32x4  __attribute__((ext_vector_type(4)));
typedef __bf16 bf16x8 __attribute__((ext_vector_type(8)));
typedef int    i32x4  __attribute__((ext_vector_type(4)));
typedef ushort u16x4  __attribute__((ext_vector_type(4)));

#define NN 262144
#define CI 32
#define CO 64
#define KK 27
#define WPAD 40              // 80B rows: 16B-aligned, near-minimal LDS serialization
#define THREADS 1024
#define TILE_T 4             // A-tiles (16 octants each) per wave
#define OCT_PER_WAVE (16 * TILE_T)          // 64
#define OCT_PER_BLOCK (OCT_PER_WAVE * 16)   // 1024 (16 waves)

__device__ __forceinline__ ushort f2bf_rne(float f) {
  union { float f; unsigned u; } v; v.f = f;
  unsigned u = v.u;
  u += 0x7FFFu + ((u >> 16) & 1u);
  return (ushort)(u >> 16);
}

// fp32 -> bf16 (RNE) pre-pass: 8.4M elements, 4/thread
__global__ __launch_bounds__(256) void cvt_input_kernel(
    const float* __restrict__ in, ushort* __restrict__ out) {
  const int i = (blockIdx.x * 256 + threadIdx.x) * 4;
  f32x4 v = *(const f32x4*)(in + i);
  u16x4 o;
  o[0] = f2bf_rne(v[0]); o[1] = f2bf_rne(v[1]);
  o[2] = f2bf_rne(v[2]); o[3] = f2bf_rne(v[3]);
  *(u16x4*)(out + i) = o;
}

template <bool BF16IN>
__global__ __launch_bounds__(THREADS, 4) void octconv_kernel(
    const void* __restrict__ input_v,   // bf16[N][32] (ws) or f32[N][32]
    const float* __restrict__ weights,  // [27][32][64]
    const int*   __restrict__ neigh,    // [N][27]
    float*       __restrict__ out)      // [N][64]
{
  // Weights bf16, transposed to [k][o][c] so a B-fragment
  // (lane l: B[8*(l>>4)+j][l&15]) is one contiguous 16B ds_read_b128.
  __shared__ ushort w_lds[KK * CO * WPAD];   // 138,240 B

  const int tid = threadIdx.x;
  for (int i = tid; i < KK * CI * CO; i += THREADS) {
    const int k   = i >> 11;
    const int rem = i & 2047;
    const int c   = rem >> 6;
    const int o   = rem & 63;
    w_lds[(k * CO + o) * WPAD + c] = f2bf_rne(weights[i]);
  }
  __syncthreads();

  const int wave = tid >> 6;
  const int lane = tid & 63;
  const int g    = lane >> 4;   // channel-chunk selector (8 channels)
  const int r16  = lane & 15;   // A row within tile / B column
  const int oct_base = blockIdx.x * OCT_PER_BLOCK + wave * OCT_PER_WAVE;

  // Per-lane neighbor row pointers for the 4 A-tiles
  const int* __restrict__ nptr[TILE_T];
#pragma unroll
  for (int t = 0; t < TILE_T; ++t)
    nptr[t] = neigh + (size_t)(oct_base + t * 16 + r16) * KK;

  f32x4 acc[TILE_T][4];
#pragma unroll
  for (int t = 0; t < TILE_T; ++t)
#pragma unroll
    for (int b = 0; b < 4; ++b)
      acc[t][b] = (f32x4){0.f, 0.f, 0.f, 0.f};

#pragma unroll
  for (int k = 0; k < KK; ++k) {
    // 4 B-fragments (o-tiles), reused across 4 A-tiles
    bf16x8 bf[4];
#pragma unroll
    for (int b = 0; b < 4; ++b)
      bf[b] = *(const bf16x8*)&w_lds[(k * CO + r16 + 16 * b) * WPAD + g * 8];

#pragma unroll
    for (int t = 0; t < TILE_T; ++t) {
      const int idx = nptr[t][k];
      bf16x8 a;
      if (BF16IN) {
        const ushort* __restrict__ ip =
            (const ushort*)input_v + (size_t)(idx < 0 ? 0 : idx) * CI + g * 8;
        i32x4 u = *(const i32x4*)ip;
        if (idx < 0) u = (i32x4){0, 0, 0, 0};
        a = __builtin_bit_cast(bf16x8, u);
      } else {
        const float* __restrict__ ip =
            (const float*)input_v + (size_t)(idx < 0 ? 0 : idx) * CI + g * 8;
        f32x4 v0 = *(const f32x4*)ip;
        f32x4 v1 = *(const f32x4*)(ip + 4);
        if (idx < 0) {
          v0 = (f32x4){0.f, 0.f, 0.f, 0.f};
          v1 = (f32x4){0.f, 0.f, 0.f, 0.f};
        }
        a[0] = (__bf16)v0[0]; a[1] = (__bf16)v0[1];
        a[2] = (__bf16)v0[2]; a[3] = (__bf16)v0[3];
        a[4] = (__bf16)v1[0]; a[5] = (__bf16)v1[1];
        a[6] = (__bf16)v1[2]; a[7] = (__bf16)v1[3];
      }
#pragma unroll
      for (int b = 0; b < 4; ++b)
        acc[t][b] = __builtin_amdgcn_mfma_f32_16x16x32_bf16(a, bf[b], acc[t][b], 0, 0, 0);
    }
  }

  // C/D layout: col = lane&15, row = (lane>>4)*4 + reg
#pragma unroll
  for (int t = 0; t < TILE_T; ++t) {
    float* __restrict__ obase =
        out + (size_t)(oct_base + t * 16 + g * 4) * CO + r16;
#pragma unroll
    for (int rr = 0; rr < 4; ++rr) {
#pragma unroll
      for (int b = 0; b < 4; ++b)
        obase[rr * CO + 16 * b] = acc[t][b][rr];
    }
  }
}

extern "C" void kernel_launch(void* const* d_in, const int* in_sizes, int n_in,
                              void* d_out, int out_size, void* d_ws, size_t ws_size,
                              hipStream_t stream) {
  const float* input   = (const float*)d_in[0];
  const float* weights = (const float*)d_in[1];
  const int*   neigh   = (const int*)d_in[2];
  float*       out     = (float*)d_out;

  const size_t bf16_bytes = (size_t)NN * CI * sizeof(ushort);  // 16 MiB
  const bool use_bf16 = ws_size >= bf16_bytes;

  dim3 grid(NN / OCT_PER_BLOCK);   // 256 blocks

  if (use_bf16) {
    ushort* in_bf16 = (ushort*)d_ws;
    cvt_input_kernel<<<dim3((NN * CI) / (256 * 4)), 256, 0, stream>>>(input, in_bf16);
    octconv_kernel<true><<<grid, THREADS, 0, stream>>>(in_bf16, weights, neigh, out);
  } else {
    octconv_kernel<false><<<grid, THREADS, 0, stream>>>(input, weights, neigh, out);
  }
}